// Round 8
// baseline (335.791 us; speedup 1.0000x reference)
//
#include <hip/hip_runtime.h>
#include <stdint.h>

#define BATCH 2
#define NANCH 100000
#define NCLS 80
#define TOPK 300
#define NSLICE (BATCH * NCLS)                 // 160
#define CAND 2048
#define FLATN (NCLS * TOPK)                   // 24000
#define ELEMS_PER_IMG (NANCH * NCLS)          // 8,000,000
#define F4TOTAL ((BATCH * ELEMS_PER_IMG) / 4) // 4,000,000
#define CUT 0.992f                            // expected ~800 cand/slice on uniform data
#define CHUNK_F4 2048                         // 256 thr x 8 f4
#define NBLK ((F4TOTAL + CHUNK_F4 - 1) / CHUNK_F4)  // 1954
#define NBPAD 2048

// ---------- IoU, bit-exact vs reference (no FMA contraction) ----------
__device__ __forceinline__ bool iou_gt_half(float4 a, float4 b) {
#pragma clang fp contract(off)
    float areaA = (a.z - a.x) * (a.w - a.y);
    float areaB = (b.z - b.x) * (b.w - b.y);
    float ty = fmaxf(a.x, b.x);
    float tx = fmaxf(a.y, b.y);
    float by = fminf(a.z, b.z);
    float bx = fminf(a.w, b.w);
    float hh = fmaxf(by - ty, 0.0f);
    float ww = fmaxf(bx - tx, 0.0f);
    float inter = hh * ww;
    float un = (areaA + areaB) - inter;
    float iou = inter / fmaxf(un, 1e-8f);
    return iou > 0.5f;
}

// ---------- K1: per-block per-slice counts (no global atomics) ----------
__global__ __launch_bounds__(256) void k1_count(const float* __restrict__ cls,
                                                uint32_t* __restrict__ blockcnt) {
    __shared__ uint32_t cnt[NSLICE];
    const int tid = threadIdx.x, blk = blockIdx.x;
    for (int i = tid; i < NSLICE; i += 256) cnt[i] = 0;
    __syncthreads();
    const float4* p = reinterpret_cast<const float4*>(cls);
    const int base = blk * CHUNK_F4;
#pragma unroll
    for (int j = 0; j < 8; ++j) {
        int i = base + j * 256 + tid;
        if (i < F4TOTAL) {
            float4 v = p[i];
            if (v.x >= CUT || v.y >= CUT || v.z >= CUT || v.w >= CUT) {
                uint32_t eg = (uint32_t)i * 4u;
                int b = (eg >= (uint32_t)ELEMS_PER_IMG) ? 1 : 0;
                uint32_t e = eg - (uint32_t)b * (uint32_t)ELEMS_PER_IMG;
                uint32_t c = e % NCLS;
                float arr[4] = {v.x, v.y, v.z, v.w};
#pragma unroll
                for (int q = 0; q < 4; ++q)
                    if (arr[q] >= CUT) atomicAdd(&cnt[b * NCLS + (int)c + q], 1u);
            }
        }
    }
    __syncthreads();
    for (int s = tid; s < NSLICE; s += 256) blockcnt[(size_t)s * NBPAD + blk] = cnt[s];
}

// ---------- K2: per-slice exclusive prefix scan over blocks ----------
__global__ __launch_bounds__(256) void k2_scan(const uint32_t* __restrict__ blockcnt,
                                               uint32_t* __restrict__ blockbase,
                                               uint32_t* __restrict__ ccount) {
    __shared__ uint32_t A[NBPAD], B[NBPAD];
    const int s = blockIdx.x, tid = threadIdx.x;
    for (int i = tid; i < NBPAD; i += 256)
        A[i] = (i >= 1 && i <= NBLK) ? blockcnt[(size_t)s * NBPAD + i - 1] : 0u;
    __syncthreads();
    uint32_t* src = A;
    uint32_t* dst = B;
    for (int off = 1; off < NBPAD; off <<= 1) {
        for (int i = tid; i < NBPAD; i += 256)
            dst[i] = src[i] + ((i >= off) ? src[i - off] : 0u);
        __syncthreads();
        uint32_t* t = src; src = dst; dst = t;
    }
    for (int i = tid; i < NBLK; i += 256) blockbase[(size_t)s * NBPAD + i] = src[i];
    if (tid == 0) ccount[s] = src[NBLK];
}

// ---------- K3: emit candidates to exclusive reserved positions ----------
__global__ __launch_bounds__(256) void k3_emit(const float* __restrict__ cls,
                                               const uint32_t* __restrict__ blockbase,
                                               uint64_t* __restrict__ cand) {
    __shared__ uint32_t cur[NSLICE];
    const int tid = threadIdx.x, blk = blockIdx.x;
    for (int i = tid; i < NSLICE; i += 256) cur[i] = 0;
    __syncthreads();
    const float4* p = reinterpret_cast<const float4*>(cls);
    const int base = blk * CHUNK_F4;
#pragma unroll
    for (int j = 0; j < 8; ++j) {
        int i = base + j * 256 + tid;
        if (i < F4TOTAL) {
            float4 v = p[i];
            if (v.x >= CUT || v.y >= CUT || v.z >= CUT || v.w >= CUT) {
                uint32_t eg = (uint32_t)i * 4u;
                int b = (eg >= (uint32_t)ELEMS_PER_IMG) ? 1 : 0;
                uint32_t e = eg - (uint32_t)b * (uint32_t)ELEMS_PER_IMG;
                uint32_t n = e / NCLS;
                uint32_t c = e - n * NCLS;
                float arr[4] = {v.x, v.y, v.z, v.w};
#pragma unroll
                for (int q = 0; q < 4; ++q) {
                    float s = arr[q];
                    if (s >= CUT) {
                        int slice = b * NCLS + (int)c + q;
                        uint32_t off = atomicAdd(&cur[slice], 1u);
                        uint32_t pos = blockbase[(size_t)slice * NBPAD + blk] + off;
                        if (pos < CAND)
                            cand[(size_t)slice * CAND + pos] =
                                ((uint64_t)__float_as_uint(s) << 32) | (uint64_t)(~n);
                    }
                }
            }
        }
    }
}

// ---------- K4: generic fixup (exits immediately when superset is valid) ----------
__global__ __launch_bounds__(256) void k4_fixup(const float* __restrict__ cls,
                                                uint32_t* __restrict__ ccount,
                                                uint64_t* __restrict__ cand) {
    const int slice = blockIdx.x;
    const uint32_t cnt0 = ccount[slice];
    if (cnt0 >= (uint32_t)TOPK && cnt0 <= (uint32_t)CAND) return;  // fast path
    const int b = slice / NCLS, c = slice % NCLS;
    const float* col = cls + (size_t)b * ELEMS_PER_IMG + c;
    __shared__ uint32_t h[128];
    __shared__ uint32_t nvalid;
    __shared__ int Tb;
    const int tid = threadIdx.x;
    for (int i = tid; i < 128; i += 256) h[i] = 0;
    if (tid == 0) nvalid = 0;
    __syncthreads();
    for (int i = tid; i < NANCH; i += 256) {
        float s = col[(size_t)i * NCLS];
        if (s > 0.05f) {
            int bn = min((int)(fminf(s, 0.9999999f) * 128.0f), 127);
            atomicAdd(&h[bn], 1u);
            atomicAdd(&nvalid, 1u);
        }
    }
    __syncthreads();
    if (tid == 0) {
        uint32_t need = min((uint32_t)TOPK, nvalid);
        uint32_t cum = 0;
        int T = 0;
        if (need > 0) {
            for (int d = 127; d >= 0; --d) {
                if (cum + h[d] >= need) { T = d; break; }
                cum += h[d];
            }
        } else {
            T = 128;
        }
        Tb = T;
        ccount[slice] = 0;
    }
    __syncthreads();
    const int T = Tb;
    for (int i = tid; i < NANCH; i += 256) {
        float s = col[(size_t)i * NCLS];
        if (s > 0.05f) {
            int bn = min((int)(fminf(s, 0.9999999f) * 128.0f), 127);
            if (bn >= T) {
                uint32_t slot = atomicAdd(&ccount[slice], 1u);
                if (slot < CAND)
                    cand[(size_t)slice * CAND + slot] =
                        ((uint64_t)__float_as_uint(s) << 32) | (uint64_t)(~(uint32_t)i);
            }
        }
    }
}

// ---------- K5: per-slice sort + IoU + register/ballot NMS + stage ----------
__global__ __launch_bounds__(512) void k5_nms(const float* __restrict__ boxes,
                                              const uint32_t* __restrict__ ccount,
                                              const uint64_t* __restrict__ cand,
                                              uint64_t* __restrict__ staged,
                                              int* __restrict__ nsel) {
    __shared__ uint64_t keys[CAND];                       // 16 KB
    __shared__ float4 box[TOPK];                          // 4.8 KB
    __shared__ unsigned long long supT[TOPK][5];          // 12 KB: supT[r][g] bit l = r suppresses (64g+l)
    __shared__ uint8_t kept[TOPK];
    const int tid = threadIdx.x;
    const int slice = blockIdx.x;
    const int b = slice / NCLS, c = slice % NCLS;
    const uint32_t cnt = min(ccount[slice], (uint32_t)CAND);
    const int SN = (cnt <= 1024u) ? 1024 : 2048;
    for (int i = tid; i < SN; i += 512)
        keys[i] = (i < (int)cnt) ? cand[(size_t)slice * CAND + i] : 0ull;

    // bitonic sort ascending (rank r desc = keys[SN-1-r])
    for (int k = 2; k <= SN; k <<= 1) {
        for (int j = k >> 1; j > 0; j >>= 1) {
            __syncthreads();
            for (int i = tid; i < SN; i += 512) {
                int p = i ^ j;
                if (p > i) {
                    uint64_t a = keys[i], bb = keys[p];
                    if ((a > bb) == ((i & k) == 0)) { keys[i] = bb; keys[p] = a; }
                }
            }
        }
    }
    __syncthreads();

    // gather top-K boxes; zero supT
    for (int r = tid; r < TOPK; r += 512) {
        uint64_t sk = keys[SN - 1 - r];
        uint32_t n = sk ? ~(uint32_t)sk : 0u;
        box[r] = reinterpret_cast<const float4*>(boxes)[(size_t)b * NANCH + n];
    }
    {
        unsigned long long* f = &supT[0][0];
        for (int i = tid; i < TOPK * 5; i += 512) f[i] = 0ull;
    }
    __syncthreads();

    // pairwise IoU > 0.5: pair (r1 > r2) -> row r2 suppresses col r1 (upper triangle)
    for (int t = tid; t < TOPK * TOPK; t += 512) {
        int r1 = t / TOPK, r2 = t - r1 * TOPK;
        if (r2 < r1) {
            if (iou_gt_half(box[r1], box[r2]))
                atomicOr(&supT[r2][r1 >> 6], 1ull << (r1 & 63));
        }
    }
    __syncthreads();

    // greedy NMS, wave 0: forward suppression propagation, ballot-based (no LDS chain)
    if (tid < 64) {
        const int l = tid;
        unsigned long long vmask[5];
#pragma unroll
        for (int g = 0; g < 5; ++g) {
            int bi = l + 64 * g;
            bool va = (bi < TOPK) && (keys[SN - 1 - bi] != 0ull);
            vmask[g] = __ballot(va);
        }
        uint32_t S = 0;  // bit g: box (l + 64g) suppressed by kept set
#pragma unroll
        for (int i = 0; i < TOPK; ++i) {
            const int gi = i >> 6;
            unsigned long long bal = __ballot(((S >> gi) & 1u) != 0u);
            bool sup = (bal >> (i & 63)) & 1ull;
            bool va = (vmask[gi] >> (i & 63)) & 1ull;
            bool keep = va && !sup;
            if (l == 0) kept[i] = keep ? (uint8_t)1 : (uint8_t)0;
            uint32_t add = 0;
#pragma unroll
            for (int g = 0; g < 5; ++g) {
                if (g >= gi) {  // boxes in groups < gi already decided
                    unsigned long long w = supT[i][g];
                    add |= ((uint32_t)((w >> l) & 1ull)) << g;
                }
            }
            S |= keep ? add : 0u;
        }
    }
    __syncthreads();

    // stage final keys + anchor indices
    for (int r = tid; r < TOPK; r += 512) {
        uint64_t sk = keys[SN - 1 - r];
        uint32_t flat = (uint32_t)c * TOPK + (uint32_t)r;
        uint32_t n = sk ? ~(uint32_t)sk : 0u;
        nsel[(size_t)b * FLATN + flat] = (int)n;
        staged[(size_t)b * FLATN + flat] =
            (kept[r] ? ((sk & 0xFFFFFFFF00000000ull) | (uint64_t)(~flat)) : 0ull);
    }
}

// ---------- K6: per-image top-300 via 64-step value binary search (register keys) ----------
__global__ __launch_bounds__(1024) void k6_final(const float* __restrict__ boxes,
                                                 const uint64_t* __restrict__ staged,
                                                 const int* __restrict__ nsel,
                                                 float* __restrict__ out) {
    __shared__ uint32_t wsum[2][16];
    __shared__ uint64_t sel[512];
    __shared__ uint64_t rankedKey[TOPK];
    __shared__ uint32_t selCount;
    const int tid = threadIdx.x;
    const int lane = tid & 63;
    const int wid = tid >> 6;
    const int b = blockIdx.x;
    const uint64_t* keys = staged + (size_t)b * FLATN;

    uint64_t kk[24];
#pragma unroll
    for (int j = 0; j < 24; ++j) {
        int i = tid + j * 1024;
        kk[j] = (i < FLATN) ? keys[i] : 0ull;
    }
    if (tid == 0) selCount = 0;
    for (int i = tid; i < 512; i += 1024) sel[i] = 0ull;
    for (int i = tid; i < TOPK; i += 1024) rankedKey[i] = 0ull;

    {
        int c = 0;
#pragma unroll
        for (int j = 0; j < 24; ++j) c += (kk[j] != 0ull) ? 1 : 0;
#pragma unroll
        for (int off = 32; off > 0; off >>= 1) c += __shfl_down(c, off);
        if (lane == 0) wsum[0][wid] = (uint32_t)c;
    }
    __syncthreads();
    uint32_t total = 0;
#pragma unroll
    for (int w = 0; w < 16; ++w) total += wsum[0][w];
    const uint32_t need = total < (uint32_t)TOPK ? total : (uint32_t)TOPK;

    uint64_t lo = 1ull, hi = ~0ull;
    int par = 1;
    for (int it = 0; it < 64; ++it) {
        uint64_t mid = lo + ((hi - lo) >> 1);
        int c = 0;
#pragma unroll
        for (int j = 0; j < 24; ++j) c += (kk[j] >= mid) ? 1 : 0;
#pragma unroll
        for (int off = 32; off > 0; off >>= 1) c += __shfl_down(c, off);
        if (lane == 0) wsum[par][wid] = (uint32_t)c;
        __syncthreads();
        uint32_t tot = 0;
#pragma unroll
        for (int w = 0; w < 16; ++w) tot += wsum[par][w];
        if (tot >= need) lo = mid; else hi = mid;
        par ^= 1;
    }
    const uint64_t thresh = lo;

    if (need > 0) {
#pragma unroll
        for (int j = 0; j < 24; ++j) {
            uint64_t v = kk[j];
            if (v >= thresh && v != 0ull) {
                uint32_t pos = atomicAdd(&selCount, 1u);
                if (pos < 512) sel[pos] = v;
            }
        }
    }
    __syncthreads();

    for (int s = tid; s < 512; s += 1024) {
        uint64_t mine = sel[s];
        if (mine != 0ull) {
            int rank = 0;
            for (int j2 = 0; j2 < 512; ++j2) rank += (sel[j2] > mine) ? 1 : 0;
            if (rank < TOPK) rankedKey[rank] = mine;
        }
    }
    __syncthreads();

    float* outBoxes = out;
    float* outScores = out + BATCH * TOPK * 4;
    float* outLabels = out + BATCH * TOPK * 4 + BATCH * TOPK;
    for (int r0 = tid; r0 < TOPK; r0 += 1024) {
        uint64_t kkv = rankedKey[r0];
        if (kkv != 0ull) {
            uint32_t flat = ~(uint32_t)kkv;
            uint32_t c = flat / TOPK;
            uint32_t n = (uint32_t)nsel[(size_t)b * FLATN + flat];
            float4 bx = reinterpret_cast<const float4*>(boxes)[(size_t)b * NANCH + n];
            reinterpret_cast<float4*>(outBoxes)[(size_t)b * TOPK + r0] = bx;
            outScores[b * TOPK + r0] = __uint_as_float((uint32_t)(kkv >> 32));
            outLabels[b * TOPK + r0] = (float)c;
        } else {
            reinterpret_cast<float4*>(outBoxes)[(size_t)b * TOPK + r0] =
                make_float4(-1.0f, -1.0f, -1.0f, -1.0f);
            outScores[b * TOPK + r0] = -1.0f;
            outLabels[b * TOPK + r0] = -1.0f;
        }
    }
}

extern "C" void kernel_launch(void* const* d_in, const int* in_sizes, int n_in,
                              void* d_out, int out_size, void* d_ws, size_t ws_size,
                              hipStream_t stream) {
    const float* boxes = (const float*)d_in[0];          // [2,100000,4]
    const float* cls   = (const float*)d_in[1];          // [2,100000,80]
    float* out = (float*)d_out;                          // 3600 floats
    char* ws = (char*)d_ws;

    size_t off = 0;
    uint32_t* blockcnt = (uint32_t*)(ws + off);
    off += (size_t)NSLICE * NBPAD * 4;                   // 1,310,720
    uint32_t* blockbase = (uint32_t*)(ws + off);
    off += (size_t)NSLICE * NBPAD * 4;                   // 1,310,720
    uint32_t* ccount = (uint32_t*)(ws + off); off += 4096;
    uint64_t* cand = (uint64_t*)(ws + off);
    off += (size_t)NSLICE * CAND * 8;                    // 2,621,440
    uint64_t* staged = (uint64_t*)(ws + off);
    off += (size_t)BATCH * FLATN * 8;                    // 384,000
    int* nsel = (int*)(ws + off);
    off += (size_t)BATCH * FLATN * 4;                    // 192,000

    k1_count<<<NBLK, 256, 0, stream>>>(cls, blockcnt);
    k2_scan<<<NSLICE, 256, 0, stream>>>(blockcnt, blockbase, ccount);
    k3_emit<<<NBLK, 256, 0, stream>>>(cls, blockbase, cand);
    k4_fixup<<<NSLICE, 256, 0, stream>>>(cls, ccount, cand);
    k5_nms<<<NSLICE, 512, 0, stream>>>(boxes, ccount, cand, staged, nsel);
    k6_final<<<BATCH, 1024, 0, stream>>>(boxes, staged, nsel, out);
}

// Round 9
// 247.487 us; speedup vs baseline: 1.3568x; 1.3568x over previous
//
#include <hip/hip_runtime.h>
#include <stdint.h>

#define BATCH 2
#define NANCH 100000
#define NCLS 80
#define TOPK 300
#define NSLICE (BATCH * NCLS)                 // 160
#define CAND 2048
#define FLATN (NCLS * TOPK)                   // 24000
#define ELEMS_PER_IMG (NANCH * NCLS)          // 8,000,000
#define F4TOTAL ((BATCH * ELEMS_PER_IMG) / 4) // 4,000,000
#define CUT 0.992f                            // expected ~800 cand/slice on uniform data
#define CHUNK_F4 2048                         // 256 thr x 8 f4
#define NBLK ((F4TOTAL + CHUNK_F4 - 1) / CHUNK_F4)  // 1954
#define NBPAD 2048

// ---------- IoU, bit-exact vs reference (no FMA contraction) ----------
__device__ __forceinline__ bool iou_gt_half(float4 a, float4 b) {
#pragma clang fp contract(off)
    float areaA = (a.z - a.x) * (a.w - a.y);
    float areaB = (b.z - b.x) * (b.w - b.y);
    float ty = fmaxf(a.x, b.x);
    float tx = fmaxf(a.y, b.y);
    float by = fminf(a.z, b.z);
    float bx = fminf(a.w, b.w);
    float hh = fmaxf(by - ty, 0.0f);
    float ww = fmaxf(bx - tx, 0.0f);
    float inter = hh * ww;
    float un = (areaA + areaB) - inter;
    float iou = inter / fmaxf(un, 1e-8f);
    return iou > 0.5f;
}

// ---------- K1: per-block per-slice counts (no global atomics) ----------
__global__ __launch_bounds__(256) void k1_count(const float* __restrict__ cls,
                                                uint32_t* __restrict__ blockcnt) {
    __shared__ uint32_t cnt[NSLICE];
    const int tid = threadIdx.x, blk = blockIdx.x;
    for (int i = tid; i < NSLICE; i += 256) cnt[i] = 0;
    __syncthreads();
    const float4* p = reinterpret_cast<const float4*>(cls);
    const int base = blk * CHUNK_F4;
#pragma unroll
    for (int j = 0; j < 8; ++j) {
        int i = base + j * 256 + tid;
        if (i < F4TOTAL) {
            float4 v = p[i];
            if (v.x >= CUT || v.y >= CUT || v.z >= CUT || v.w >= CUT) {
                uint32_t eg = (uint32_t)i * 4u;
                int b = (eg >= (uint32_t)ELEMS_PER_IMG) ? 1 : 0;
                uint32_t e = eg - (uint32_t)b * (uint32_t)ELEMS_PER_IMG;
                uint32_t c = e % NCLS;
                float arr[4] = {v.x, v.y, v.z, v.w};
#pragma unroll
                for (int q = 0; q < 4; ++q)
                    if (arr[q] >= CUT) atomicAdd(&cnt[b * NCLS + (int)c + q], 1u);
            }
        }
    }
    __syncthreads();
    for (int s = tid; s < NSLICE; s += 256) blockcnt[(size_t)s * NBPAD + blk] = cnt[s];
}

// ---------- K2: per-slice exclusive prefix scan over blocks ----------
__global__ __launch_bounds__(256) void k2_scan(const uint32_t* __restrict__ blockcnt,
                                               uint32_t* __restrict__ blockbase,
                                               uint32_t* __restrict__ ccount) {
    __shared__ uint32_t A[NBPAD], B[NBPAD];
    const int s = blockIdx.x, tid = threadIdx.x;
    for (int i = tid; i < NBPAD; i += 256)
        A[i] = (i >= 1 && i <= NBLK) ? blockcnt[(size_t)s * NBPAD + i - 1] : 0u;
    __syncthreads();
    uint32_t* src = A;
    uint32_t* dst = B;
    for (int off = 1; off < NBPAD; off <<= 1) {
        for (int i = tid; i < NBPAD; i += 256)
            dst[i] = src[i] + ((i >= off) ? src[i - off] : 0u);
        __syncthreads();
        uint32_t* t = src; src = dst; dst = t;
    }
    for (int i = tid; i < NBLK; i += 256) blockbase[(size_t)s * NBPAD + i] = src[i];
    if (tid == 0) ccount[s] = src[NBLK];
}

// ---------- K3: emit candidates to exclusive reserved positions ----------
__global__ __launch_bounds__(256) void k3_emit(const float* __restrict__ cls,
                                               const uint32_t* __restrict__ blockbase,
                                               uint64_t* __restrict__ cand) {
    __shared__ uint32_t cur[NSLICE];
    const int tid = threadIdx.x, blk = blockIdx.x;
    for (int i = tid; i < NSLICE; i += 256) cur[i] = 0;
    __syncthreads();
    const float4* p = reinterpret_cast<const float4*>(cls);
    const int base = blk * CHUNK_F4;
#pragma unroll
    for (int j = 0; j < 8; ++j) {
        int i = base + j * 256 + tid;
        if (i < F4TOTAL) {
            float4 v = p[i];
            if (v.x >= CUT || v.y >= CUT || v.z >= CUT || v.w >= CUT) {
                uint32_t eg = (uint32_t)i * 4u;
                int b = (eg >= (uint32_t)ELEMS_PER_IMG) ? 1 : 0;
                uint32_t e = eg - (uint32_t)b * (uint32_t)ELEMS_PER_IMG;
                uint32_t n = e / NCLS;
                uint32_t c = e - n * NCLS;
                float arr[4] = {v.x, v.y, v.z, v.w};
#pragma unroll
                for (int q = 0; q < 4; ++q) {
                    float s = arr[q];
                    if (s >= CUT) {
                        int slice = b * NCLS + (int)c + q;
                        uint32_t off = atomicAdd(&cur[slice], 1u);
                        uint32_t pos = blockbase[(size_t)slice * NBPAD + blk] + off;
                        if (pos < CAND)
                            cand[(size_t)slice * CAND + pos] =
                                ((uint64_t)__float_as_uint(s) << 32) | (uint64_t)(~n);
                    }
                }
            }
        }
    }
}

// ---------- K4: generic fixup (exits immediately when superset is valid) ----------
__global__ __launch_bounds__(256) void k4_fixup(const float* __restrict__ cls,
                                                uint32_t* __restrict__ ccount,
                                                uint64_t* __restrict__ cand) {
    const int slice = blockIdx.x;
    const uint32_t cnt0 = ccount[slice];
    if (cnt0 >= (uint32_t)TOPK && cnt0 <= (uint32_t)CAND) return;  // fast path
    const int b = slice / NCLS, c = slice % NCLS;
    const float* col = cls + (size_t)b * ELEMS_PER_IMG + c;
    __shared__ uint32_t h[128];
    __shared__ uint32_t nvalid;
    __shared__ int Tb;
    const int tid = threadIdx.x;
    for (int i = tid; i < 128; i += 256) h[i] = 0;
    if (tid == 0) nvalid = 0;
    __syncthreads();
    for (int i = tid; i < NANCH; i += 256) {
        float s = col[(size_t)i * NCLS];
        if (s > 0.05f) {
            int bn = min((int)(fminf(s, 0.9999999f) * 128.0f), 127);
            atomicAdd(&h[bn], 1u);
            atomicAdd(&nvalid, 1u);
        }
    }
    __syncthreads();
    if (tid == 0) {
        uint32_t need = min((uint32_t)TOPK, nvalid);
        uint32_t cum = 0;
        int T = 0;
        if (need > 0) {
            for (int d = 127; d >= 0; --d) {
                if (cum + h[d] >= need) { T = d; break; }
                cum += h[d];
            }
        } else {
            T = 128;
        }
        Tb = T;
        ccount[slice] = 0;
    }
    __syncthreads();
    const int T = Tb;
    for (int i = tid; i < NANCH; i += 256) {
        float s = col[(size_t)i * NCLS];
        if (s > 0.05f) {
            int bn = min((int)(fminf(s, 0.9999999f) * 128.0f), 127);
            if (bn >= T) {
                uint32_t slot = atomicAdd(&ccount[slice], 1u);
                if (slot < CAND)
                    cand[(size_t)slice * CAND + slot] =
                        ((uint64_t)__float_as_uint(s) << 32) | (uint64_t)(~(uint32_t)i);
            }
        }
    }
}

// ---------- K5: per-slice sort + IoU + register-resident ballot NMS + stage ----------
__global__ __launch_bounds__(512) void k5_nms(const float* __restrict__ boxes,
                                              const uint32_t* __restrict__ ccount,
                                              const uint64_t* __restrict__ cand,
                                              uint64_t* __restrict__ staged,
                                              int* __restrict__ nsel) {
    __shared__ uint64_t keys[CAND];                       // 16 KB
    __shared__ float4 box[TOPK];                          // 4.8 KB
    __shared__ unsigned long long rowm[TOPK][5];          // 12 KB: rowm[i][w] bit b = box (64w+b) suppresses i (j<i only)
    __shared__ unsigned long long kw[5];                  // kept bitmask
    const int tid = threadIdx.x;
    const int slice = blockIdx.x;
    const int b = slice / NCLS, c = slice % NCLS;
    const uint32_t cnt = min(ccount[slice], (uint32_t)CAND);
    const int SN = (cnt <= 1024u) ? 1024 : 2048;
    for (int i = tid; i < SN; i += 512)
        keys[i] = (i < (int)cnt) ? cand[(size_t)slice * CAND + i] : 0ull;

    // bitonic sort ascending (rank r desc = keys[SN-1-r])
    for (int k = 2; k <= SN; k <<= 1) {
        for (int j = k >> 1; j > 0; j >>= 1) {
            __syncthreads();
            for (int i = tid; i < SN; i += 512) {
                int p = i ^ j;
                if (p > i) {
                    uint64_t a = keys[i], bb = keys[p];
                    if ((a > bb) == ((i & k) == 0)) { keys[i] = bb; keys[p] = a; }
                }
            }
        }
    }
    __syncthreads();

    // gather top-K boxes; zero rowm
    for (int r = tid; r < TOPK; r += 512) {
        uint64_t sk = keys[SN - 1 - r];
        uint32_t n = sk ? ~(uint32_t)sk : 0u;
        box[r] = reinterpret_cast<const float4*>(boxes)[(size_t)b * NANCH + n];
    }
    {
        unsigned long long* f = &rowm[0][0];
        for (int i = tid; i < TOPK * 5; i += 512) f[i] = 0ull;
    }
    __syncthreads();

    // pairwise IoU > 0.5: r2 < r1 -> r2 suppresses r1 -> set bit r2 in row r1
    for (int t = tid; t < TOPK * TOPK; t += 512) {
        int r1 = t / TOPK, r2 = t - r1 * TOPK;
        if (r2 < r1) {
            if (iou_gt_half(box[r1], box[r2]))
                atomicOr(&rowm[r1][r2 >> 6], 1ull << (r2 & 63));
        }
    }
    __syncthreads();

    // greedy NMS, wave 0: suppression matrix fully in registers, no LDS in loop
    if (tid < 64) {
        const int l = tid;
        // rb[s][w]: which boxes (64w..64w+63) suppress my box r = l + 64s
        unsigned long long rb[5][5];
#pragma unroll
        for (int s = 0; s < 5; ++s) {
            int r = l + 64 * s;
            bool in = r < TOPK;
#pragma unroll
            for (int w = 0; w < 5; ++w) rb[s][w] = in ? rowm[r][w] : 0ull;
        }
        unsigned long long vm[5];
#pragma unroll
        for (int s = 0; s < 5; ++s) {
            int bi = l + 64 * s;
            vm[s] = __ballot((bi < TOPK) && (keys[SN - 1 - bi] != 0ull));
        }
        uint32_t S = 0;  // bit s: my box l+64s suppressed by kept set
#pragma unroll
        for (int wi = 0; wi < 5; ++wi) {
            const int tmax = (wi == 4) ? (TOPK - 256) : 64;
            unsigned long long kwc = 0ull;
            uint32_t sbit = (S >> wi) & 1u;
            for (int t = 0; t < tmax; ++t) {
                unsigned long long bal = __ballot(sbit != 0u);
                bool sup = ((bal >> t) & 1ull) != 0ull;     // uniform
                bool va = ((vm[wi] >> t) & 1ull) != 0ull;   // uniform
                if (va && !sup) {                           // uniform branch
                    kwc |= (1ull << t);
#pragma unroll
                    for (int s = 0; s < 5; ++s)
                        S |= ((uint32_t)((rb[s][wi] >> t) & 1ull)) << s;
                    sbit = (S >> wi) & 1u;
                }
            }
            if (l == 0) kw[wi] = kwc;
        }
    }
    __syncthreads();

    // stage final keys + anchor indices
    for (int r = tid; r < TOPK; r += 512) {
        uint64_t sk = keys[SN - 1 - r];
        uint32_t flat = (uint32_t)c * TOPK + (uint32_t)r;
        uint32_t n = sk ? ~(uint32_t)sk : 0u;
        bool kept = ((kw[r >> 6] >> (r & 63)) & 1ull) != 0ull;
        nsel[(size_t)b * FLATN + flat] = (int)n;
        staged[(size_t)b * FLATN + flat] =
            (kept ? ((sk & 0xFFFFFFFF00000000ull) | (uint64_t)(~flat)) : 0ull);
    }
}

// ---------- K6: per-image top-300 via 64-step value binary search (register keys) ----------
__global__ __launch_bounds__(1024) void k6_final(const float* __restrict__ boxes,
                                                 const uint64_t* __restrict__ staged,
                                                 const int* __restrict__ nsel,
                                                 float* __restrict__ out) {
    __shared__ uint32_t wsum[2][16];
    __shared__ uint64_t sel[512];
    __shared__ uint64_t rankedKey[TOPK];
    __shared__ uint32_t selCount;
    const int tid = threadIdx.x;
    const int lane = tid & 63;
    const int wid = tid >> 6;
    const int b = blockIdx.x;
    const uint64_t* keys = staged + (size_t)b * FLATN;

    uint64_t kk[24];
#pragma unroll
    for (int j = 0; j < 24; ++j) {
        int i = tid + j * 1024;
        kk[j] = (i < FLATN) ? keys[i] : 0ull;
    }
    if (tid == 0) selCount = 0;
    for (int i = tid; i < 512; i += 1024) sel[i] = 0ull;
    for (int i = tid; i < TOPK; i += 1024) rankedKey[i] = 0ull;

    {
        int c = 0;
#pragma unroll
        for (int j = 0; j < 24; ++j) c += (kk[j] != 0ull) ? 1 : 0;
#pragma unroll
        for (int off = 32; off > 0; off >>= 1) c += __shfl_down(c, off);
        if (lane == 0) wsum[0][wid] = (uint32_t)c;
    }
    __syncthreads();
    uint32_t total = 0;
#pragma unroll
    for (int w = 0; w < 16; ++w) total += wsum[0][w];
    const uint32_t need = total < (uint32_t)TOPK ? total : (uint32_t)TOPK;

    uint64_t lo = 1ull, hi = ~0ull;
    int par = 1;
    for (int it = 0; it < 64; ++it) {
        uint64_t mid = lo + ((hi - lo) >> 1);
        int c = 0;
#pragma unroll
        for (int j = 0; j < 24; ++j) c += (kk[j] >= mid) ? 1 : 0;
#pragma unroll
        for (int off = 32; off > 0; off >>= 1) c += __shfl_down(c, off);
        if (lane == 0) wsum[par][wid] = (uint32_t)c;
        __syncthreads();
        uint32_t tot = 0;
#pragma unroll
        for (int w = 0; w < 16; ++w) tot += wsum[par][w];
        if (tot >= need) lo = mid; else hi = mid;
        par ^= 1;
    }
    const uint64_t thresh = lo;

    if (need > 0) {
#pragma unroll
        for (int j = 0; j < 24; ++j) {
            uint64_t v = kk[j];
            if (v >= thresh && v != 0ull) {
                uint32_t pos = atomicAdd(&selCount, 1u);
                if (pos < 512) sel[pos] = v;
            }
        }
    }
    __syncthreads();

    for (int s = tid; s < 512; s += 1024) {
        uint64_t mine = sel[s];
        if (mine != 0ull) {
            int rank = 0;
            for (int j2 = 0; j2 < 512; ++j2) rank += (sel[j2] > mine) ? 1 : 0;
            if (rank < TOPK) rankedKey[rank] = mine;
        }
    }
    __syncthreads();

    float* outBoxes = out;
    float* outScores = out + BATCH * TOPK * 4;
    float* outLabels = out + BATCH * TOPK * 4 + BATCH * TOPK;
    for (int r0 = tid; r0 < TOPK; r0 += 1024) {
        uint64_t kkv = rankedKey[r0];
        if (kkv != 0ull) {
            uint32_t flat = ~(uint32_t)kkv;
            uint32_t c = flat / TOPK;
            uint32_t n = (uint32_t)nsel[(size_t)b * FLATN + flat];
            float4 bx = reinterpret_cast<const float4*>(boxes)[(size_t)b * NANCH + n];
            reinterpret_cast<float4*>(outBoxes)[(size_t)b * TOPK + r0] = bx;
            outScores[b * TOPK + r0] = __uint_as_float((uint32_t)(kkv >> 32));
            outLabels[b * TOPK + r0] = (float)c;
        } else {
            reinterpret_cast<float4*>(outBoxes)[(size_t)b * TOPK + r0] =
                make_float4(-1.0f, -1.0f, -1.0f, -1.0f);
            outScores[b * TOPK + r0] = -1.0f;
            outLabels[b * TOPK + r0] = -1.0f;
        }
    }
}

extern "C" void kernel_launch(void* const* d_in, const int* in_sizes, int n_in,
                              void* d_out, int out_size, void* d_ws, size_t ws_size,
                              hipStream_t stream) {
    const float* boxes = (const float*)d_in[0];          // [2,100000,4]
    const float* cls   = (const float*)d_in[1];          // [2,100000,80]
    float* out = (float*)d_out;                          // 3600 floats
    char* ws = (char*)d_ws;

    size_t off = 0;
    uint32_t* blockcnt = (uint32_t*)(ws + off);
    off += (size_t)NSLICE * NBPAD * 4;                   // 1,310,720
    uint32_t* blockbase = (uint32_t*)(ws + off);
    off += (size_t)NSLICE * NBPAD * 4;                   // 1,310,720
    uint32_t* ccount = (uint32_t*)(ws + off); off += 4096;
    uint64_t* cand = (uint64_t*)(ws + off);
    off += (size_t)NSLICE * CAND * 8;                    // 2,621,440
    uint64_t* staged = (uint64_t*)(ws + off);
    off += (size_t)BATCH * FLATN * 8;                    // 384,000
    int* nsel = (int*)(ws + off);
    off += (size_t)BATCH * FLATN * 4;                    // 192,000

    k1_count<<<NBLK, 256, 0, stream>>>(cls, blockcnt);
    k2_scan<<<NSLICE, 256, 0, stream>>>(blockcnt, blockbase, ccount);
    k3_emit<<<NBLK, 256, 0, stream>>>(cls, blockbase, cand);
    k4_fixup<<<NSLICE, 256, 0, stream>>>(cls, ccount, cand);
    k5_nms<<<NSLICE, 512, 0, stream>>>(boxes, ccount, cand, staged, nsel);
    k6_final<<<BATCH, 1024, 0, stream>>>(boxes, staged, nsel, out);
}

// Round 10
// 235.548 us; speedup vs baseline: 1.4256x; 1.0507x over previous
//
#include <hip/hip_runtime.h>
#include <stdint.h>

#define BATCH 2
#define NANCH 100000
#define NCLS 80
#define TOPK 300
#define NSLICE (BATCH * NCLS)                 // 160
#define CAND 2048
#define FLATN (NCLS * TOPK)                   // 24000
#define ELEMS_PER_IMG (NANCH * NCLS)          // 8,000,000
#define F4TOTAL ((BATCH * ELEMS_PER_IMG) / 4) // 4,000,000
#define CUT 0.992f                            // expected ~800 cand/slice on uniform data
#define CHUNK_F4 2048                         // 256 thr x 8 f4
#define NBLK ((F4TOTAL + CHUNK_F4 - 1) / CHUNK_F4)  // 1954
#define NBPAD 2048
#define HCAP 128                              // per-block hit-list capacity (mean 65.5, +7.7 sigma)

// ---------- IoU, bit-exact vs reference (no FMA contraction) ----------
__device__ __forceinline__ bool iou_gt_half(float4 a, float4 b) {
#pragma clang fp contract(off)
    float areaA = (a.z - a.x) * (a.w - a.y);
    float areaB = (b.z - b.x) * (b.w - b.y);
    float ty = fmaxf(a.x, b.x);
    float tx = fmaxf(a.y, b.y);
    float by = fminf(a.z, b.z);
    float bx = fminf(a.w, b.w);
    float hh = fmaxf(by - ty, 0.0f);
    float ww = fmaxf(bx - tx, 0.0f);
    float inter = hh * ww;
    float un = (areaA + areaB) - inter;
    float iou = inter / fmaxf(un, 1e-8f);
    return iou > 0.5f;
}

// ---------- K1: per-block per-slice counts + compact hit list (no global atomics) ----------
__global__ __launch_bounds__(256) void k1_count(const float* __restrict__ cls,
                                                uint32_t* __restrict__ blockcnt,
                                                uint32_t* __restrict__ hitcnt,
                                                uint64_t* __restrict__ hitKey,
                                                uint8_t* __restrict__ hitSlice) {
    __shared__ uint32_t cnt[NSLICE];
    __shared__ uint32_t hcnt;
    __shared__ uint64_t hK[HCAP];
    __shared__ uint8_t hS[HCAP];
    const int tid = threadIdx.x, blk = blockIdx.x;
    for (int i = tid; i < NSLICE; i += 256) cnt[i] = 0;
    if (tid == 0) hcnt = 0;
    __syncthreads();
    const float4* p = reinterpret_cast<const float4*>(cls);
    const int base = blk * CHUNK_F4;
#pragma unroll
    for (int j = 0; j < 8; ++j) {
        int i = base + j * 256 + tid;
        if (i < F4TOTAL) {
            float4 v = p[i];
            if (v.x >= CUT || v.y >= CUT || v.z >= CUT || v.w >= CUT) {
                uint32_t eg = (uint32_t)i * 4u;
                int b = (eg >= (uint32_t)ELEMS_PER_IMG) ? 1 : 0;
                uint32_t e = eg - (uint32_t)b * (uint32_t)ELEMS_PER_IMG;
                uint32_t n = e / NCLS;
                uint32_t c = e - n * NCLS;
                float arr[4] = {v.x, v.y, v.z, v.w};
#pragma unroll
                for (int q = 0; q < 4; ++q) {
                    float s = arr[q];
                    if (s >= CUT) {
                        uint32_t slice = (uint32_t)(b * NCLS) + c + (uint32_t)q;
                        atomicAdd(&cnt[slice], 1u);
                        uint32_t idx = atomicAdd(&hcnt, 1u);
                        if (idx < HCAP) {
                            hK[idx] = ((uint64_t)__float_as_uint(s) << 32) | (uint64_t)(~n);
                            hS[idx] = (uint8_t)slice;
                        }
                    }
                }
            }
        }
    }
    __syncthreads();
    for (int s = tid; s < NSLICE; s += 256) blockcnt[(size_t)s * NBPAD + blk] = cnt[s];
    uint32_t nh = hcnt;
    if (tid == 0) hitcnt[blk] = nh;
    uint32_t nw = nh < (uint32_t)HCAP ? nh : (uint32_t)HCAP;
    for (int i = tid; i < (int)nw; i += 256) {
        hitKey[(size_t)blk * HCAP + i] = hK[i];
        hitSlice[(size_t)blk * HCAP + i] = hS[i];
    }
}

// ---------- K2: per-slice exclusive prefix scan over blocks (two-level, 1 barrier) ----------
__global__ __launch_bounds__(256) void k2_scan(const uint32_t* __restrict__ blockcnt,
                                               uint32_t* __restrict__ blockbase,
                                               uint32_t* __restrict__ ccount) {
    __shared__ uint32_t wsum[4];
    const int s = blockIdx.x, tid = threadIdx.x;
    const int lane = tid & 63, wid = tid >> 6;
    uint32_t v[8], ex[8];
    uint32_t tot = 0;
#pragma unroll
    for (int q = 0; q < 8; ++q) {
        int j = tid * 8 + q;
        v[q] = (j < NBLK) ? blockcnt[(size_t)s * NBPAD + j] : 0u;
        ex[q] = tot;
        tot += v[q];
    }
    uint32_t x = tot;
#pragma unroll
    for (int d = 1; d < 64; d <<= 1) {
        uint32_t y = __shfl_up(x, d);
        if (lane >= d) x += y;
    }
    if (lane == 63) wsum[wid] = x;
    uint32_t wexcl = x - tot;
    __syncthreads();
    uint32_t wbase = 0;
#pragma unroll
    for (int w = 0; w < 4; ++w) wbase += (w < wid) ? wsum[w] : 0u;
    uint32_t base = wbase + wexcl;
#pragma unroll
    for (int q = 0; q < 8; ++q) {
        int j = tid * 8 + q;
        if (j < NBLK) blockbase[(size_t)s * NBPAD + j] = base + ex[q];
    }
    if (tid == 255) ccount[s] = base + tot;
}

// ---------- K3: scatter hit lists to exclusive positions (2MB, not 64MB) ----------
__global__ __launch_bounds__(128) void k3_emit(const float* __restrict__ cls,
                                               const uint32_t* __restrict__ blockbase,
                                               const uint32_t* __restrict__ hitcnt,
                                               const uint64_t* __restrict__ hitKey,
                                               const uint8_t* __restrict__ hitSlice,
                                               uint64_t* __restrict__ cand) {
    __shared__ uint32_t cur[NSLICE];
    const int tid = threadIdx.x, blk = blockIdx.x;
    for (int i = tid; i < NSLICE; i += 128) cur[i] = 0;
    __syncthreads();
    const uint32_t nh = hitcnt[blk];
    if (nh <= (uint32_t)HCAP) {
        if (tid < (int)nh) {
            uint32_t slice = hitSlice[(size_t)blk * HCAP + tid];
            uint64_t key = hitKey[(size_t)blk * HCAP + tid];
            uint32_t off = atomicAdd(&cur[slice], 1u);
            uint32_t pos = blockbase[(size_t)slice * NBPAD + blk] + off;
            if (pos < CAND) cand[(size_t)slice * CAND + pos] = key;
        }
    } else {
        // overflow fallback (pathological data): rescan this block's raw range
        const float4* p = reinterpret_cast<const float4*>(cls);
        const int base = blk * CHUNK_F4;
        for (int t = tid; t < CHUNK_F4; t += 128) {
            int i = base + t;
            if (i < F4TOTAL) {
                float4 v = p[i];
                if (v.x >= CUT || v.y >= CUT || v.z >= CUT || v.w >= CUT) {
                    uint32_t eg = (uint32_t)i * 4u;
                    int b = (eg >= (uint32_t)ELEMS_PER_IMG) ? 1 : 0;
                    uint32_t e = eg - (uint32_t)b * (uint32_t)ELEMS_PER_IMG;
                    uint32_t n = e / NCLS;
                    uint32_t c = e - n * NCLS;
                    float arr[4] = {v.x, v.y, v.z, v.w};
#pragma unroll
                    for (int q = 0; q < 4; ++q) {
                        float s = arr[q];
                        if (s >= CUT) {
                            int slice = b * NCLS + (int)c + q;
                            uint32_t off = atomicAdd(&cur[slice], 1u);
                            uint32_t pos = blockbase[(size_t)slice * NBPAD + blk] + off;
                            if (pos < CAND)
                                cand[(size_t)slice * CAND + pos] =
                                    ((uint64_t)__float_as_uint(s) << 32) | (uint64_t)(~n);
                        }
                    }
                }
            }
        }
    }
}

// ---------- K4: generic fixup (exits immediately when superset is valid) ----------
__global__ __launch_bounds__(256) void k4_fixup(const float* __restrict__ cls,
                                                uint32_t* __restrict__ ccount,
                                                uint64_t* __restrict__ cand) {
    const int slice = blockIdx.x;
    const uint32_t cnt0 = ccount[slice];
    if (cnt0 >= (uint32_t)TOPK && cnt0 <= (uint32_t)CAND) return;  // fast path
    const int b = slice / NCLS, c = slice % NCLS;
    const float* col = cls + (size_t)b * ELEMS_PER_IMG + c;
    __shared__ uint32_t h[128];
    __shared__ uint32_t nvalid;
    __shared__ int Tb;
    const int tid = threadIdx.x;
    for (int i = tid; i < 128; i += 256) h[i] = 0;
    if (tid == 0) nvalid = 0;
    __syncthreads();
    for (int i = tid; i < NANCH; i += 256) {
        float s = col[(size_t)i * NCLS];
        if (s > 0.05f) {
            int bn = min((int)(fminf(s, 0.9999999f) * 128.0f), 127);
            atomicAdd(&h[bn], 1u);
            atomicAdd(&nvalid, 1u);
        }
    }
    __syncthreads();
    if (tid == 0) {
        uint32_t need = min((uint32_t)TOPK, nvalid);
        uint32_t cum = 0;
        int T = 0;
        if (need > 0) {
            for (int d = 127; d >= 0; --d) {
                if (cum + h[d] >= need) { T = d; break; }
                cum += h[d];
            }
        } else {
            T = 128;
        }
        Tb = T;
        ccount[slice] = 0;
    }
    __syncthreads();
    const int T = Tb;
    for (int i = tid; i < NANCH; i += 256) {
        float s = col[(size_t)i * NCLS];
        if (s > 0.05f) {
            int bn = min((int)(fminf(s, 0.9999999f) * 128.0f), 127);
            if (bn >= T) {
                uint32_t slot = atomicAdd(&ccount[slice], 1u);
                if (slot < CAND)
                    cand[(size_t)slice * CAND + slot] =
                        ((uint64_t)__float_as_uint(s) << 32) | (uint64_t)(~(uint32_t)i);
            }
        }
    }
}

// ---------- K5: per-slice sort + IoU + register-resident ballot NMS + stage ----------
// launch_bounds(512,2): only 1 block/CU possible (160 blocks/256 CUs) -> allow ~256 VGPR
// so the rb[5][5] suppression matrix actually lives in registers (round-9: VGPR=20 = spilled).
__global__ __launch_bounds__(512, 2) void k5_nms(const float* __restrict__ boxes,
                                                 const uint32_t* __restrict__ ccount,
                                                 const uint64_t* __restrict__ cand,
                                                 uint64_t* __restrict__ staged,
                                                 int* __restrict__ nsel) {
    __shared__ uint64_t keys[CAND];                       // 16 KB
    __shared__ float4 box[TOPK];                          // 4.8 KB
    __shared__ unsigned long long rowm[TOPK][5];          // 12 KB
    __shared__ unsigned long long kw[5];                  // kept bitmask
    const int tid = threadIdx.x;
    const int slice = blockIdx.x;
    const int b = slice / NCLS, c = slice % NCLS;
    const uint32_t cnt = min(ccount[slice], (uint32_t)CAND);
    const int SN = (cnt <= 1024u) ? 1024 : 2048;
    for (int i = tid; i < SN; i += 512)
        keys[i] = (i < (int)cnt) ? cand[(size_t)slice * CAND + i] : 0ull;

    // bitonic sort ascending (rank r desc = keys[SN-1-r])
    for (int k = 2; k <= SN; k <<= 1) {
        for (int j = k >> 1; j > 0; j >>= 1) {
            __syncthreads();
            for (int i = tid; i < SN; i += 512) {
                int p = i ^ j;
                if (p > i) {
                    uint64_t a = keys[i], bb = keys[p];
                    if ((a > bb) == ((i & k) == 0)) { keys[i] = bb; keys[p] = a; }
                }
            }
        }
    }
    __syncthreads();

    // gather top-K boxes; zero rowm
    for (int r = tid; r < TOPK; r += 512) {
        uint64_t sk = keys[SN - 1 - r];
        uint32_t n = sk ? ~(uint32_t)sk : 0u;
        box[r] = reinterpret_cast<const float4*>(boxes)[(size_t)b * NANCH + n];
    }
    {
        unsigned long long* f = &rowm[0][0];
        for (int i = tid; i < TOPK * 5; i += 512) f[i] = 0ull;
    }
    __syncthreads();

    // pairwise IoU > 0.5: r2 < r1 -> r2 suppresses r1 -> set bit r2 in row r1
    for (int t = tid; t < TOPK * TOPK; t += 512) {
        int r1 = t / TOPK, r2 = t - r1 * TOPK;
        if (r2 < r1) {
            if (iou_gt_half(box[r1], box[r2]))
                atomicOr(&rowm[r1][r2 >> 6], 1ull << (r2 & 63));
        }
    }
    __syncthreads();

    // greedy NMS, wave 0: suppression matrix fully in registers, no LDS in loop
    if (tid < 64) {
        const int l = tid;
        unsigned long long rb[5][5];
#pragma unroll
        for (int s = 0; s < 5; ++s) {
            int r = l + 64 * s;
            bool in = r < TOPK;
#pragma unroll
            for (int w = 0; w < 5; ++w) rb[s][w] = in ? rowm[r][w] : 0ull;
        }
        unsigned long long vm[5];
#pragma unroll
        for (int s = 0; s < 5; ++s) {
            int bi = l + 64 * s;
            vm[s] = __ballot((bi < TOPK) && (keys[SN - 1 - bi] != 0ull));
        }
        uint32_t S = 0;  // bit s: my box l+64s suppressed by kept set
#pragma unroll
        for (int wi = 0; wi < 5; ++wi) {
            const int tmax = (wi == 4) ? (TOPK - 256) : 64;
            unsigned long long kwc = 0ull;
            uint32_t sbit = (S >> wi) & 1u;
            for (int t = 0; t < tmax; ++t) {
                unsigned long long bal = __ballot(sbit != 0u);
                bool sup = ((bal >> t) & 1ull) != 0ull;     // uniform
                bool va = ((vm[wi] >> t) & 1ull) != 0ull;   // uniform
                if (va && !sup) {                           // uniform branch
                    kwc |= (1ull << t);
#pragma unroll
                    for (int s = 0; s < 5; ++s)
                        S |= ((uint32_t)((rb[s][wi] >> t) & 1ull)) << s;
                    sbit = (S >> wi) & 1u;
                }
            }
            if (l == 0) kw[wi] = kwc;
        }
    }
    __syncthreads();

    // stage final keys + anchor indices
    for (int r = tid; r < TOPK; r += 512) {
        uint64_t sk = keys[SN - 1 - r];
        uint32_t flat = (uint32_t)c * TOPK + (uint32_t)r;
        uint32_t n = sk ? ~(uint32_t)sk : 0u;
        bool kept = ((kw[r >> 6] >> (r & 63)) & 1ull) != 0ull;
        nsel[(size_t)b * FLATN + flat] = (int)n;
        staged[(size_t)b * FLATN + flat] =
            (kept ? ((sk & 0xFFFFFFFF00000000ull) | (uint64_t)(~flat)) : 0ull);
    }
}

// ---------- K6: per-image top-300 via 64-step value binary search (register keys) ----------
__global__ __launch_bounds__(1024) void k6_final(const float* __restrict__ boxes,
                                                 const uint64_t* __restrict__ staged,
                                                 const int* __restrict__ nsel,
                                                 float* __restrict__ out) {
    __shared__ uint32_t wsum[2][16];
    __shared__ uint64_t sel[512];
    __shared__ uint64_t rankedKey[TOPK];
    __shared__ uint32_t selCount;
    const int tid = threadIdx.x;
    const int lane = tid & 63;
    const int wid = tid >> 6;
    const int b = blockIdx.x;
    const uint64_t* keys = staged + (size_t)b * FLATN;

    uint64_t kk[24];
#pragma unroll
    for (int j = 0; j < 24; ++j) {
        int i = tid + j * 1024;
        kk[j] = (i < FLATN) ? keys[i] : 0ull;
    }
    if (tid == 0) selCount = 0;
    for (int i = tid; i < 512; i += 1024) sel[i] = 0ull;
    for (int i = tid; i < TOPK; i += 1024) rankedKey[i] = 0ull;

    {
        int c = 0;
#pragma unroll
        for (int j = 0; j < 24; ++j) c += (kk[j] != 0ull) ? 1 : 0;
#pragma unroll
        for (int off = 32; off > 0; off >>= 1) c += __shfl_down(c, off);
        if (lane == 0) wsum[0][wid] = (uint32_t)c;
    }
    __syncthreads();
    uint32_t total = 0;
#pragma unroll
    for (int w = 0; w < 16; ++w) total += wsum[0][w];
    const uint32_t need = total < (uint32_t)TOPK ? total : (uint32_t)TOPK;

    uint64_t lo = 1ull, hi = ~0ull;
    int par = 1;
    for (int it = 0; it < 64; ++it) {
        uint64_t mid = lo + ((hi - lo) >> 1);
        int c = 0;
#pragma unroll
        for (int j = 0; j < 24; ++j) c += (kk[j] >= mid) ? 1 : 0;
#pragma unroll
        for (int off = 32; off > 0; off >>= 1) c += __shfl_down(c, off);
        if (lane == 0) wsum[par][wid] = (uint32_t)c;
        __syncthreads();
        uint32_t tot = 0;
#pragma unroll
        for (int w = 0; w < 16; ++w) tot += wsum[par][w];
        if (tot >= need) lo = mid; else hi = mid;
        par ^= 1;
    }
    const uint64_t thresh = lo;

    if (need > 0) {
#pragma unroll
        for (int j = 0; j < 24; ++j) {
            uint64_t v = kk[j];
            if (v >= thresh && v != 0ull) {
                uint32_t pos = atomicAdd(&selCount, 1u);
                if (pos < 512) sel[pos] = v;
            }
        }
    }
    __syncthreads();

    for (int s = tid; s < 512; s += 1024) {
        uint64_t mine = sel[s];
        if (mine != 0ull) {
            int rank = 0;
            for (int j2 = 0; j2 < 512; ++j2) rank += (sel[j2] > mine) ? 1 : 0;
            if (rank < TOPK) rankedKey[rank] = mine;
        }
    }
    __syncthreads();

    float* outBoxes = out;
    float* outScores = out + BATCH * TOPK * 4;
    float* outLabels = out + BATCH * TOPK * 4 + BATCH * TOPK;
    for (int r0 = tid; r0 < TOPK; r0 += 1024) {
        uint64_t kkv = rankedKey[r0];
        if (kkv != 0ull) {
            uint32_t flat = ~(uint32_t)kkv;
            uint32_t c = flat / TOPK;
            uint32_t n = (uint32_t)nsel[(size_t)b * FLATN + flat];
            float4 bx = reinterpret_cast<const float4*>(boxes)[(size_t)b * NANCH + n];
            reinterpret_cast<float4*>(outBoxes)[(size_t)b * TOPK + r0] = bx;
            outScores[b * TOPK + r0] = __uint_as_float((uint32_t)(kkv >> 32));
            outLabels[b * TOPK + r0] = (float)c;
        } else {
            reinterpret_cast<float4*>(outBoxes)[(size_t)b * TOPK + r0] =
                make_float4(-1.0f, -1.0f, -1.0f, -1.0f);
            outScores[b * TOPK + r0] = -1.0f;
            outLabels[b * TOPK + r0] = -1.0f;
        }
    }
}

extern "C" void kernel_launch(void* const* d_in, const int* in_sizes, int n_in,
                              void* d_out, int out_size, void* d_ws, size_t ws_size,
                              hipStream_t stream) {
    const float* boxes = (const float*)d_in[0];          // [2,100000,4]
    const float* cls   = (const float*)d_in[1];          // [2,100000,80]
    float* out = (float*)d_out;                          // 3600 floats
    char* ws = (char*)d_ws;

    size_t off = 0;
    uint32_t* blockcnt = (uint32_t*)(ws + off);
    off += (size_t)NSLICE * NBPAD * 4;                   // 1,310,720
    uint32_t* blockbase = (uint32_t*)(ws + off);
    off += (size_t)NSLICE * NBPAD * 4;                   // 1,310,720
    uint32_t* ccount = (uint32_t*)(ws + off); off += 4096;
    uint32_t* hitcnt = (uint32_t*)(ws + off); off += NBPAD * 4;          // 8,192
    uint64_t* hitKey = (uint64_t*)(ws + off); off += (size_t)NBPAD * HCAP * 8;   // 2,097,152
    uint8_t* hitSlice = (uint8_t*)(ws + off); off += (size_t)NBPAD * HCAP;       // 262,144
    uint64_t* cand = (uint64_t*)(ws + off);
    off += (size_t)NSLICE * CAND * 8;                    // 2,621,440
    uint64_t* staged = (uint64_t*)(ws + off);
    off += (size_t)BATCH * FLATN * 8;                    // 384,000
    int* nsel = (int*)(ws + off);
    off += (size_t)BATCH * FLATN * 4;                    // 192,000

    k1_count<<<NBLK, 256, 0, stream>>>(cls, blockcnt, hitcnt, hitKey, hitSlice);
    k2_scan<<<NSLICE, 256, 0, stream>>>(blockcnt, blockbase, ccount);
    k3_emit<<<NBLK, 128, 0, stream>>>(cls, blockbase, hitcnt, hitKey, hitSlice, cand);
    k4_fixup<<<NSLICE, 256, 0, stream>>>(cls, ccount, cand);
    k5_nms<<<NSLICE, 512, 0, stream>>>(boxes, ccount, cand, staged, nsel);
    k6_final<<<BATCH, 1024, 0, stream>>>(boxes, staged, nsel, out);
}